// Round 3
// baseline (705.085 us; speedup 1.0000x reference)
//
#include <hip/hip_runtime.h>
#include <stdint.h>

#define NVOX 400000
#define KTAPS 27
#define TILE 128
#define CAP 1024
#define NCHUNK_CAP (CAP / 16 + KTAPS)   // 91

typedef __bf16 bf16x8 __attribute__((ext_vector_type(8)));
typedef float floatx4 __attribute__((ext_vector_type(4)));

__device__ __forceinline__ uint32_t f2bf(float f) {
  uint32_t u = __builtin_bit_cast(uint32_t, f);
  u += 0x7fffu + ((u >> 16) & 1u);
  return u >> 16;
}

// Weight convert + transpose: Wt[k][co][ci] = bf16(W[k][ci][co]). 432 blocks.
__global__ void k_wt(const float* __restrict__ W, unsigned short* __restrict__ Wt) {
  int i = blockIdx.x * 256 + threadIdx.x;
  int k = i >> 12;
  int rem = i & 4095;
  int ci = rem >> 6;
  int co = rem & 63;
  Wt[(k << 12) + (co << 6) + ci] = (unsigned short)f2bf(W[i]);
}

// Feats convert: fp32 -> bf16, 4 float4 per thread. Grid 6250 blocks.
__global__ void k_feats(const float4* __restrict__ F, uint2* __restrict__ Fb) {
  int i0 = blockIdx.x * 1024 + threadIdx.x;
#pragma unroll
  for (int j = 0; j < 4; ++j) {
    int i = i0 + j * 256;
    float4 v = F[i];
    uint2 o;
    o.x = f2bf(v.x) | (f2bf(v.y) << 16);
    o.y = f2bf(v.z) | (f2bf(v.w) << 16);
    Fb[i] = o;
  }
}

// Sparse gather-GEMM conv, wave-autonomous chunks, no inner barriers.
// Block = 128 output voxels, 256 threads = 4 waves. Compaction builds per-tap
// (row, idx) pair lists; <=16-row chunks are distributed round-robin to waves.
// A wave gathers a chunk's A rows DIRECTLY into the 16x16x32 MFMA A-fragment
// (lane l -> row l&15, ci-slice l>>4) from bf16 feats (2 x 16B per lane),
// 3-deep register pipeline (8 VGPR/slot in flight), multiplies against all 64
// couts of W[k] (8 MFMAs, B from L2), scatter-adds D into a shared LDS
// accumulator via ds-atomics. No __launch_bounds__ occupancy floor: LDS caps
// at 3 blocks/CU; RA must NOT spill the pipeline (R2 failure mode: 160 live
// regs squeezed into 68 -> scratch storm).
template<bool FB>
__global__ __launch_bounds__(256) void k_conv(
    const float* __restrict__ feats,
    const unsigned short* __restrict__ featsb,  // [NVOX][64] bf16 (FB=true)
    const unsigned short* __restrict__ Wt,      // [k][co][ci] bf16
    const float* __restrict__ bias,
    const int* __restrict__ nbr,                // [27][NVOX]
    float* __restrict__ out) {                  // [NVOX][64]

  __shared__ alignas(16) float accS[TILE * 72];          // 36864 B, pitch 72
  __shared__ int pairIdx[CAP];                           // 4096 B
  __shared__ unsigned short pairRow[CAP];                // 2048 B
  __shared__ unsigned long long masksS[KTAPS * 2];       // 432 B
  __shared__ int woff[KTAPS * 2 + 1];                    // 220 B
  __shared__ unsigned int chunkTab[NCHUNK_CAP];          // 364 B: k<<16 | start<<5 | len
  __shared__ int nChunksS;

  const int t = threadIdx.x;
  const int w = t >> 6;
  const int l = t & 63;

  // Bijective chunked XCD swizzle (m204): consecutive work -> same XCD L2.
  const int nwg = gridDim.x;
  const int q = nwg >> 3, r8 = nwg & 7;
  const int xcd = blockIdx.x & 7, hi = blockIdx.x >> 3;
  const int wg = (xcd < r8 ? xcd * (q + 1) : r8 * (q + 1) + (xcd - r8) * q) + hi;
  const int v0 = wg * TILE;

  // zero accumulator
  {
    float4 z = make_float4(0.f, 0.f, 0.f, 0.f);
    float4* a4 = (float4*)accS;
#pragma unroll
    for (int i = 0; i < 9; ++i) a4[t + i * 256] = z;
  }

  // ---- compaction pass 1: ballot masks per (tap, wave) ----
#pragma unroll
  for (int k = 0; k < KTAPS; ++k) {
    int id = (t < TILE) ? nbr[(size_t)k * NVOX + v0 + t] : -1;
    unsigned long long m = __ballot(id >= 0);
    if (l == 0 && w < 2) masksS[k * 2 + w] = m;
  }
  __syncthreads();
  // exclusive prefix over the 54 (tap,wave) counts -> pair offsets (wave 0)
  if (w == 0) {
    int c = (l < KTAPS * 2) ? __popcll(masksS[l]) : 0;
#pragma unroll
    for (int d = 1; d < 64; d <<= 1) { int o = __shfl_up(c, d); if (l >= d) c += o; }
    if (l < KTAPS * 2) woff[l + 1] = c;
    if (l == 0) woff[0] = 0;
  }
  __syncthreads();
  // ---- compaction pass 2: write (row, idx) pairs grouped by tap ----
#pragma unroll
  for (int k = 0; k < KTAPS; ++k) {
    int id = (t < TILE) ? nbr[(size_t)k * NVOX + v0 + t] : -1;
    if (id >= 0) {
      unsigned long long m = masksS[k * 2 + w];
      int pos = woff[k * 2 + w] + __popcll(m & ((1ull << l) - 1ull));
      if (pos < CAP) { pairRow[pos] = (unsigned short)t; pairIdx[pos] = id; }
    }
  }
  // chunk table: tap k -> ceil(cnt/16) chunks of <=16 rows (wave 0)
  if (w == 0) {
    int b0 = 0, cnt = 0;
    if (l < KTAPS) {
      b0 = min(woff[2 * l], CAP);
      cnt = min(woff[2 * l + 2], CAP) - b0;
    }
    int nch = (cnt + 15) >> 4;
    int inc = nch;
#pragma unroll
    for (int d = 1; d < 64; d <<= 1) { int o = __shfl_up(inc, d); if (l >= d) inc += o; }
    int base = inc - nch;
    for (int j = 0; j < nch; ++j) {
      int st = b0 + 16 * j;
      int ln = min(16, cnt - 16 * j);
      chunkTab[base + j] = ((unsigned)l << 16) | ((unsigned)st << 5) | (unsigned)ln;
    }
    if (l == KTAPS - 1) nChunksS = inc;
  }
  __syncthreads();
  const int nc = nChunksS;

  const int r16 = l & 15;   // A row within chunk / B cout-within-quadrant
  const int hk = l >> 4;    // 8-channel ci slice (fragment K position)

// Issue chunk cc's A-gather into 2 named uint4 regs (stays in flight).
#define ISSUE(Mv, A0v, A1v, cc) do {                                   \
    if ((cc) < nc) {                                                   \
      Mv = chunkTab[(cc)];                                             \
      int st_ = (int)((Mv >> 5) & 0x7FFu);                             \
      int ln_ = (int)(Mv & 31u);                                       \
      int ix_ = (r16 < ln_) ? pairIdx[st_ + r16] : pairIdx[st_];       \
      const unsigned short* s_ = featsb + (size_t)ix_ * 64 + hk * 8;   \
      A0v = *(const uint4*)s_;                                         \
      A1v = *(const uint4*)(s_ + 32);                                  \
    }                                                                  \
  } while (0)

// Consume a staged chunk: 8 B loads (L2) + 8 MFMAs + guarded LDS scatter-add.
#define CONSUME(Mv, A0v, A1v) do {                                               \
    const int kk_ = (int)(Mv >> 16);                                             \
    const int st_ = (int)((Mv >> 5) & 0x7FFu);                                   \
    const int ln_ = (int)(Mv & 31u);                                             \
    const unsigned short* bp_ = Wt + (kk_ << 12) + r16 * 64 + hk * 8;            \
    uint4 b0_ = *(const uint4*)bp_;                                              \
    uint4 b1_ = *(const uint4*)(bp_ + 32);                                       \
    uint4 b2_ = *(const uint4*)(bp_ + 1024);                                     \
    uint4 b3_ = *(const uint4*)(bp_ + 1056);                                     \
    uint4 b4_ = *(const uint4*)(bp_ + 2048);                                     \
    uint4 b5_ = *(const uint4*)(bp_ + 2080);                                     \
    uint4 b6_ = *(const uint4*)(bp_ + 3072);                                     \
    uint4 b7_ = *(const uint4*)(bp_ + 3104);                                     \
    bf16x8 a0_ = __builtin_bit_cast(bf16x8, A0v);                                \
    bf16x8 a1_ = __builtin_bit_cast(bf16x8, A1v);                                \
    floatx4 z_ = {0.f, 0.f, 0.f, 0.f};                                           \
    floatx4 d0_, d1_, d2_, d3_;                                                  \
    d0_ = __builtin_amdgcn_mfma_f32_16x16x32_bf16(a0_, __builtin_bit_cast(bf16x8, b0_), z_, 0, 0, 0); \
    d0_ = __builtin_amdgcn_mfma_f32_16x16x32_bf16(a1_, __builtin_bit_cast(bf16x8, b1_), d0_, 0, 0, 0);\
    d1_ = __builtin_amdgcn_mfma_f32_16x16x32_bf16(a0_, __builtin_bit_cast(bf16x8, b2_), z_, 0, 0, 0); \
    d1_ = __builtin_amdgcn_mfma_f32_16x16x32_bf16(a1_, __builtin_bit_cast(bf16x8, b3_), d1_, 0, 0, 0);\
    d2_ = __builtin_amdgcn_mfma_f32_16x16x32_bf16(a0_, __builtin_bit_cast(bf16x8, b4_), z_, 0, 0, 0); \
    d2_ = __builtin_amdgcn_mfma_f32_16x16x32_bf16(a1_, __builtin_bit_cast(bf16x8, b5_), d2_, 0, 0, 0);\
    d3_ = __builtin_amdgcn_mfma_f32_16x16x32_bf16(a0_, __builtin_bit_cast(bf16x8, b6_), z_, 0, 0, 0); \
    d3_ = __builtin_amdgcn_mfma_f32_16x16x32_bf16(a1_, __builtin_bit_cast(bf16x8, b7_), d3_, 0, 0, 0);\
    _Pragma("unroll")                                                            \
    for (int j2_ = 0; j2_ < 4; ++j2_) {                                          \
      int r2_ = hk * 4 + j2_;                                                    \
      if (r2_ < ln_) {                                                           \
        int tr_ = pairRow[st_ + r2_];                                            \
        float* p_ = accS + tr_ * 72 + r16;                                       \
        atomicAdd(p_,      d0_[j2_]);                                            \
        atomicAdd(p_ + 16, d1_[j2_]);                                            \
        atomicAdd(p_ + 32, d2_[j2_]);                                            \
        atomicAdd(p_ + 48, d3_[j2_]);                                            \
      }                                                                          \
    }                                                                            \
  } while (0)

  if (FB) {
    // ---- 3-deep software pipeline over this wave's chunks (c = w, w+4, ...) ----
    int c = w;
    unsigned m0 = 0, m1 = 0, m2 = 0;
    uint4 A00 = {0,0,0,0}, A01 = {0,0,0,0};
    uint4 A10 = {0,0,0,0}, A11 = {0,0,0,0};
    uint4 A20 = {0,0,0,0}, A21 = {0,0,0,0};
    ISSUE(m0, A00, A01, c);
    ISSUE(m1, A10, A11, c + 4);
    ISSUE(m2, A20, A21, c + 8);
    while (c < nc) {
      CONSUME(m0, A00, A01); ISSUE(m0, A00, A01, c + 12); c += 4;
      if (c >= nc) break;
      CONSUME(m1, A10, A11); ISSUE(m1, A10, A11, c + 12); c += 4;
      if (c >= nc) break;
      CONSUME(m2, A20, A21); ISSUE(m2, A20, A21, c + 12); c += 4;
    }
  } else {
    // Fallback (small workspace): serial fp32 gather + convert, no pipeline.
    for (int c = w; c < nc; c += 4) {
      unsigned m = chunkTab[c];
      int st = (int)((m >> 5) & 0x7FFu);
      int ln = (int)(m & 31u);
      int ix = (r16 < ln) ? pairIdx[st + r16] : pairIdx[st];
      const float* s = feats + (size_t)ix * 64 + hk * 8;
      float4 f0 = *(const float4*)s;
      float4 f1 = *(const float4*)(s + 4);
      float4 f2 = *(const float4*)(s + 32);
      float4 f3 = *(const float4*)(s + 36);
      uint4 A0, A1;
      A0.x = f2bf(f0.x) | (f2bf(f0.y) << 16);
      A0.y = f2bf(f0.z) | (f2bf(f0.w) << 16);
      A0.z = f2bf(f1.x) | (f2bf(f1.y) << 16);
      A0.w = f2bf(f1.z) | (f2bf(f1.w) << 16);
      A1.x = f2bf(f2.x) | (f2bf(f2.y) << 16);
      A1.y = f2bf(f2.z) | (f2bf(f2.w) << 16);
      A1.z = f2bf(f3.x) | (f2bf(f3.y) << 16);
      A1.w = f2bf(f3.z) | (f2bf(f3.w) << 16);
      CONSUME(m, A0, A1);
    }
  }
#undef ISSUE
#undef CONSUME

  // ---- epilogue: out = acc + bias (coalesced float4) ----
  __syncthreads();
  {
    int vox = t >> 1;
    int cb = (t & 1) * 32;
    float* op = out + (size_t)(v0 + vox) * 64 + cb;
    const float* ap = accS + vox * 72 + cb;
#pragma unroll
    for (int qq = 0; qq < 8; ++qq) {
      float4 v = *(const float4*)(ap + qq * 4);
      float4 bv = *(const float4*)(bias + cb + qq * 4);
      v.x += bv.x; v.y += bv.y; v.z += bv.z; v.w += bv.w;
      *(float4*)(op + qq * 4) = v;
    }
  }
}

extern "C" void kernel_launch(void* const* d_in, const int* in_sizes, int n_in,
                              void* d_out, int out_size, void* d_ws, size_t ws_size,
                              hipStream_t stream) {
  const float* feats  = (const float*)d_in[0];
  const float* weight = (const float*)d_in[1];
  const float* bias   = (const float*)d_in[2];
  const int*   nbr    = (const int*)d_in[3];
  float* out = (float*)d_out;

  unsigned short* Wt = (unsigned short*)d_ws;   // 27*4096*2 = 221184 B
  const size_t featsOff = 256 * 1024;
  const size_t fbytes = (size_t)NVOX * 64 * 2;  // 51.2 MB
  const bool bigws = ws_size >= featsOff + fbytes;

  k_wt<<<432, 256, 0, stream>>>(weight, Wt);

  const int grid = NVOX / TILE;  // 3125
  if (bigws) {
    unsigned short* Fb = (unsigned short*)((char*)d_ws + featsOff);
    k_feats<<<6250, 256, 0, stream>>>((const float4*)feats, (uint2*)Fb);
    k_conv<true><<<grid, 256, 0, stream>>>(feats, Fb, Wt, bias, nbr, out);
  } else {
    k_conv<false><<<grid, 256, 0, stream>>>(feats, nullptr, Wt, bias, nbr, out);
  }
}

// Round 4
// 470.215 us; speedup vs baseline: 1.4995x; 1.4995x over previous
//
#include <hip/hip_runtime.h>
#include <stdint.h>

#define NVOX 400000
#define KTAPS 27
#define TILE 128
#define CAP 1024
#define NCHUNK_CAP (CAP / 16 + KTAPS)   // 91

typedef __bf16 bf16x8 __attribute__((ext_vector_type(8)));
typedef float floatx4 __attribute__((ext_vector_type(4)));

__device__ __forceinline__ uint32_t f2bf(float f) {
  uint32_t u = __builtin_bit_cast(uint32_t, f);
  u += 0x7fffu + ((u >> 16) & 1u);
  return u >> 16;
}

// Weight convert + transpose: Wt[k][co][ci] = bf16(W[k][ci][co]). 432 blocks.
__global__ void k_wt(const float* __restrict__ W, unsigned short* __restrict__ Wt) {
  int i = blockIdx.x * 256 + threadIdx.x;
  int k = i >> 12;
  int rem = i & 4095;
  int ci = rem >> 6;
  int co = rem & 63;
  Wt[(k << 12) + (co << 6) + ci] = (unsigned short)f2bf(W[i]);
}

// Feats convert: fp32 -> bf16, 4 float4 per thread. Grid 6250 blocks.
__global__ void k_feats(const float4* __restrict__ F, uint2* __restrict__ Fb) {
  int i0 = blockIdx.x * 1024 + threadIdx.x;
#pragma unroll
  for (int j = 0; j < 4; ++j) {
    int i = i0 + j * 256;
    float4 v = F[i];
    uint2 o;
    o.x = f2bf(v.x) | (f2bf(v.y) << 16);
    o.y = f2bf(v.z) | (f2bf(v.w) << 16);
    Fb[i] = o;
  }
}

// Sparse gather-GEMM conv. Block = 128 output voxels, 256 threads = 4 waves.
// Compaction builds per-tap (row, idx) pair lists; <=16-row chunks.
// EVERY wave walks ALL chunks but owns one cout-QUADRANT (couts 16w..16w+16):
// per chunk it gathers the A fragment direct from bf16 feats, loads its 2
// B-fragments, does 2 MFMAs, and scatter-adds D into its PRIVATE LDS slab
// with plain read-add-write. No LDS atomics (R2/R3 bottleneck: ds_add_f32
// saturated at ~0.34 lane-ops/cy while all pipes idled), no inner barriers,
// no cross-wave row sharing by construction.
template<bool FB>
__global__ __launch_bounds__(256, 4) void k_conv(
    const float* __restrict__ feats,
    const unsigned short* __restrict__ featsb,  // [NVOX][64] bf16 (FB=true)
    const unsigned short* __restrict__ Wt,      // [k][co][ci] bf16
    const float* __restrict__ bias,
    const int* __restrict__ nbr,                // [27][NVOX]
    float* __restrict__ out) {                  // [NVOX][64]

  __shared__ alignas(16) float accS[4 * TILE * 16];      // 32768 B: wave-private slabs
  __shared__ int pairIdx[CAP];                           // 4096 B
  __shared__ unsigned short pairRow[CAP];                // 2048 B
  __shared__ unsigned long long masksS[KTAPS * 2];       // 432 B
  __shared__ int woff[KTAPS * 2 + 1];                    // 220 B
  __shared__ unsigned int chunkTab[NCHUNK_CAP];          // 364 B: k<<16 | start<<5 | len
  __shared__ int nChunksS;                               // total 39932 B -> 4 blocks/CU

  const int t = threadIdx.x;
  const int w = t >> 6;
  const int l = t & 63;

  // Bijective chunked XCD swizzle (m204): consecutive work -> same XCD L2.
  const int nwg = gridDim.x;
  const int q = nwg >> 3, r8 = nwg & 7;
  const int xcd = blockIdx.x & 7, hi = blockIdx.x >> 3;
  const int wg = (xcd < r8 ? xcd * (q + 1) : r8 * (q + 1) + (xcd - r8) * q) + hi;
  const int v0 = wg * TILE;

  float* mySlab = accS + w * (TILE * 16);

  // zero own slab (wave-private; LDS ops are in-order per wave, no barrier)
  {
    float4 z = make_float4(0.f, 0.f, 0.f, 0.f);
    float4* a4 = (float4*)mySlab;
#pragma unroll
    for (int i = 0; i < 8; ++i) a4[l + i * 64] = z;
  }

  // ---- compaction pass 1: ballot masks per (tap, wave) ----
#pragma unroll
  for (int k = 0; k < KTAPS; ++k) {
    int id = (t < TILE) ? nbr[(size_t)k * NVOX + v0 + t] : -1;
    unsigned long long m = __ballot(id >= 0);
    if (l == 0 && w < 2) masksS[k * 2 + w] = m;
  }
  __syncthreads();
  // exclusive prefix over the 54 (tap,wave) counts -> pair offsets (wave 0)
  if (w == 0) {
    int c = (l < KTAPS * 2) ? __popcll(masksS[l]) : 0;
#pragma unroll
    for (int d = 1; d < 64; d <<= 1) { int o = __shfl_up(c, d); if (l >= d) c += o; }
    if (l < KTAPS * 2) woff[l + 1] = c;
    if (l == 0) woff[0] = 0;
  }
  __syncthreads();
  // ---- compaction pass 2: write (row, idx) pairs grouped by tap ----
#pragma unroll
  for (int k = 0; k < KTAPS; ++k) {
    int id = (t < TILE) ? nbr[(size_t)k * NVOX + v0 + t] : -1;
    if (id >= 0) {
      unsigned long long m = masksS[k * 2 + w];
      int pos = woff[k * 2 + w] + __popcll(m & ((1ull << l) - 1ull));
      if (pos < CAP) { pairRow[pos] = (unsigned short)t; pairIdx[pos] = id; }
    }
  }
  // chunk table: tap k -> ceil(cnt/16) chunks of <=16 rows (wave 0)
  if (w == 0) {
    int b0 = 0, cnt = 0;
    if (l < KTAPS) {
      b0 = min(woff[2 * l], CAP);
      cnt = min(woff[2 * l + 2], CAP) - b0;
    }
    int nch = (cnt + 15) >> 4;
    int inc = nch;
#pragma unroll
    for (int d = 1; d < 64; d <<= 1) { int o = __shfl_up(inc, d); if (l >= d) inc += o; }
    int base = inc - nch;
    for (int j = 0; j < nch; ++j) {
      int st = b0 + 16 * j;
      int ln = min(16, cnt - 16 * j);
      chunkTab[base + j] = ((unsigned)l << 16) | ((unsigned)st << 5) | (unsigned)ln;
    }
    if (l == KTAPS - 1) nChunksS = inc;
  }
  __syncthreads();
  const int nc = nChunksS;

  const int r16 = l & 15;   // A row within chunk / B cout-within-quadrant
  const int hk = l >> 4;    // 8-channel ci slice (fragment K position)
  const unsigned short* WtQ = Wt + (w * 16 + r16) * 64 + hk * 8;  // quadrant base

// Issue chunk cc: A gather (bf16, direct to fragment) + this wave's B frags.
#define ISSUE(Mv, A0v, A1v, B0v, B1v, cc) do {                         \
    if ((cc) < nc) {                                                   \
      Mv = chunkTab[(cc)];                                             \
      int st_ = (int)((Mv >> 5) & 0x7FFu);                             \
      int ln_ = (int)(Mv & 31u);                                       \
      int ix_ = (r16 < ln_) ? pairIdx[st_ + r16] : pairIdx[st_];       \
      const unsigned short* s_ = featsb + (size_t)ix_ * 64 + hk * 8;   \
      A0v = *(const uint4*)s_;                                         \
      A1v = *(const uint4*)(s_ + 32);                                  \
      const unsigned short* bp_ = WtQ + ((int)(Mv >> 16) << 12);       \
      B0v = *(const uint4*)bp_;                                        \
      B1v = *(const uint4*)(bp_ + 32);                                 \
    }                                                                  \
  } while (0)

// Consume: 2 MFMAs (K=64 over two 32-ci halves) + guarded plain LDS RMW.
#define CONSUME(Mv, A0v, A1v, B0v, B1v) do {                                     \
    const int st_ = (int)((Mv >> 5) & 0x7FFu);                                   \
    const int ln_ = (int)(Mv & 31u);                                             \
    floatx4 z_ = {0.f, 0.f, 0.f, 0.f};                                           \
    floatx4 d_;                                                                  \
    d_ = __builtin_amdgcn_mfma_f32_16x16x32_bf16(                                \
        __builtin_bit_cast(bf16x8, A0v), __builtin_bit_cast(bf16x8, B0v), z_, 0, 0, 0); \
    d_ = __builtin_amdgcn_mfma_f32_16x16x32_bf16(                                \
        __builtin_bit_cast(bf16x8, A1v), __builtin_bit_cast(bf16x8, B1v), d_, 0, 0, 0); \
    _Pragma("unroll")                                                            \
    for (int j2_ = 0; j2_ < 4; ++j2_) {                                          \
      int r2_ = hk * 4 + j2_;                                                    \
      if (r2_ < ln_) {                                                           \
        int tr_ = pairRow[st_ + r2_];                                            \
        mySlab[tr_ * 16 + r16] += d_[j2_];                                       \
      }                                                                          \
    }                                                                            \
  } while (0)

  if (FB) {
    // ---- 3-deep register pipeline over ALL chunks (this wave's quadrant) ----
    unsigned m0 = 0, m1 = 0, m2 = 0;
    uint4 A00 = {0,0,0,0}, A01 = {0,0,0,0}, B00 = {0,0,0,0}, B01 = {0,0,0,0};
    uint4 A10 = {0,0,0,0}, A11 = {0,0,0,0}, B10 = {0,0,0,0}, B11 = {0,0,0,0};
    uint4 A20 = {0,0,0,0}, A21 = {0,0,0,0}, B20 = {0,0,0,0}, B21 = {0,0,0,0};
    int c = 0;
    ISSUE(m0, A00, A01, B00, B01, 0);
    ISSUE(m1, A10, A11, B10, B11, 1);
    ISSUE(m2, A20, A21, B20, B21, 2);
    while (c < nc) {
      CONSUME(m0, A00, A01, B00, B01); ISSUE(m0, A00, A01, B00, B01, c + 3); ++c;
      if (c >= nc) break;
      CONSUME(m1, A10, A11, B10, B11); ISSUE(m1, A10, A11, B10, B11, c + 3); ++c;
      if (c >= nc) break;
      CONSUME(m2, A20, A21, B20, B21); ISSUE(m2, A20, A21, B20, B21, c + 3); ++c;
    }
  } else {
    // Fallback (small workspace): serial fp32 gather + convert.
    for (int c = 0; c < nc; ++c) {
      unsigned m = chunkTab[c];
      int st = (int)((m >> 5) & 0x7FFu);
      int ln = (int)(m & 31u);
      int ix = (r16 < ln) ? pairIdx[st + r16] : pairIdx[st];
      const float* s = feats + (size_t)ix * 64 + hk * 8;
      float4 f0 = *(const float4*)s;
      float4 f1 = *(const float4*)(s + 4);
      float4 f2 = *(const float4*)(s + 32);
      float4 f3 = *(const float4*)(s + 36);
      uint4 A0, A1, B0, B1;
      A0.x = f2bf(f0.x) | (f2bf(f0.y) << 16);
      A0.y = f2bf(f0.z) | (f2bf(f0.w) << 16);
      A0.z = f2bf(f1.x) | (f2bf(f1.y) << 16);
      A0.w = f2bf(f1.z) | (f2bf(f1.w) << 16);
      A1.x = f2bf(f2.x) | (f2bf(f2.y) << 16);
      A1.y = f2bf(f2.z) | (f2bf(f2.w) << 16);
      A1.z = f2bf(f3.x) | (f2bf(f3.y) << 16);
      A1.w = f2bf(f3.z) | (f2bf(f3.w) << 16);
      const unsigned short* bp = WtQ + ((int)(m >> 16) << 12);
      B0 = *(const uint4*)bp;
      B1 = *(const uint4*)(bp + 32);
      CONSUME(m, A0, A1, B0, B1);
    }
  }
#undef ISSUE
#undef CONSUME

  // ---- epilogue: out = acc + bias (each (row,cout) lives in exactly one slab) ----
  __syncthreads();
  {
    int vox = t >> 1;
    int cb = (t & 1) * 32;
    float* op = out + (size_t)(v0 + vox) * 64 + cb;
#pragma unroll
    for (int qq = 0; qq < 8; ++qq) {
      int c0 = cb + qq * 4;
      const float* ap = accS + (c0 >> 4) * (TILE * 16) + vox * 16 + (c0 & 15);
      float4 v = *(const float4*)ap;
      float4 bv = *(const float4*)(bias + c0);
      v.x += bv.x; v.y += bv.y; v.z += bv.z; v.w += bv.w;
      *(float4*)(op + qq * 4) = v;
    }
  }
}

extern "C" void kernel_launch(void* const* d_in, const int* in_sizes, int n_in,
                              void* d_out, int out_size, void* d_ws, size_t ws_size,
                              hipStream_t stream) {
  const float* feats  = (const float*)d_in[0];
  const float* weight = (const float*)d_in[1];
  const float* bias   = (const float*)d_in[2];
  const int*   nbr    = (const int*)d_in[3];
  float* out = (float*)d_out;

  unsigned short* Wt = (unsigned short*)d_ws;   // 27*4096*2 = 221184 B
  const size_t featsOff = 256 * 1024;
  const size_t fbytes = (size_t)NVOX * 64 * 2;  // 51.2 MB
  const bool bigws = ws_size >= featsOff + fbytes;

  k_wt<<<432, 256, 0, stream>>>(weight, Wt);

  const int grid = NVOX / TILE;  // 3125
  if (bigws) {
    unsigned short* Fb = (unsigned short*)((char*)d_ws + featsOff);
    k_feats<<<6250, 256, 0, stream>>>((const float4*)feats, (uint2*)Fb);
    k_conv<true><<<grid, 256, 0, stream>>>(feats, Fb, Wt, bias, nbr, out);
  } else {
    k_conv<false><<<grid, 256, 0, stream>>>(feats, nullptr, Wt, bias, nbr, out);
  }
}

// Round 5
// 466.383 us; speedup vs baseline: 1.5118x; 1.0082x over previous
//
#include <hip/hip_runtime.h>
#include <stdint.h>

#define NVOX 400000
#define KTAPS 27
#define TILE 128
#define CAP 768
#define NCHUNK_CAP (CAP / 16 + KTAPS)   // 75

typedef __bf16 bf16x8 __attribute__((ext_vector_type(8)));
typedef float floatx4 __attribute__((ext_vector_type(4)));

__device__ __forceinline__ uint32_t f2bf(float f) {
  uint32_t u = __builtin_bit_cast(uint32_t, f);
  u += 0x7fffu + ((u >> 16) & 1u);
  return u >> 16;
}

// Weight convert + transpose: Wt[k][co][ci] = bf16(W[k][ci][co]). 432 blocks.
__global__ void k_wt(const float* __restrict__ W, unsigned short* __restrict__ Wt) {
  int i = blockIdx.x * 256 + threadIdx.x;
  int k = i >> 12;
  int rem = i & 4095;
  int ci = rem >> 6;
  int co = rem & 63;
  Wt[(k << 12) + (co << 6) + ci] = (unsigned short)f2bf(W[i]);
}

// Feats convert: fp32 -> bf16, 4 float4 per thread. Grid 6250 blocks.
__global__ void k_feats(const float4* __restrict__ F, uint2* __restrict__ Fb) {
  int i0 = blockIdx.x * 1024 + threadIdx.x;
#pragma unroll
  for (int j = 0; j < 4; ++j) {
    int i = i0 + j * 256;
    float4 v = F[i];
    uint2 o;
    o.x = f2bf(v.x) | (f2bf(v.y) << 16);
    o.y = f2bf(v.z) | (f2bf(v.w) << 16);
    Fb[i] = o;
  }
}

// Sparse gather-GEMM conv. Block = 128 output voxels, 256 threads = 4 waves.
// Compaction -> per-tap (row, idx) pair lists -> <=16-row chunks. Every wave
// walks all chunks, owns one cout-quadrant, scatter-adds into a PRIVATE LDS
// slab (no atomics). R5 changes vs R4:
//  (a) MFMA operands SWAPPED: D = W x feats, so lane's 4 D elems are 4
//      consecutive couts of ONE output row -> scatter = 1 pairRow read +
//      1 ds_read_b128 + 1 ds_write_b128 (was 12 scalar LDS ops w/ chains).
//  (b) pipeline depth 2 with minimal state (~34 regs) so the RA keeps it in
//      registers (R2-R4: declared state > allocation -> scratch round-trips
//      sharing vmcnt with in-flight gathers re-exposed full L3 latency).
//  (c) CAP 768: LDS 38.4 KB targeting 4 blocks/CU.
template<bool FB>
__global__ __launch_bounds__(256, 4) void k_conv(
    const float* __restrict__ feats,
    const unsigned short* __restrict__ featsb,  // [NVOX][64] bf16 (FB=true)
    const unsigned short* __restrict__ Wt,      // [k][co][ci] bf16
    const float* __restrict__ bias,
    const int* __restrict__ nbr,                // [27][NVOX]
    float* __restrict__ out) {                  // [NVOX][64]

  __shared__ alignas(16) float accS[4 * TILE * 16];      // 32768 B: wave-private slabs
  __shared__ int pairIdx[CAP];                           // 3072 B
  __shared__ unsigned short pairRow[CAP];                // 1536 B
  __shared__ unsigned long long masksS[KTAPS * 2];       // 432 B
  __shared__ int woff[KTAPS * 2 + 1];                    // 220 B
  __shared__ unsigned int chunkTab[NCHUNK_CAP];          // 300 B: k<<16 | start<<5 | len
  __shared__ int nChunksS;                               // ~38.3 KB total

  const int t = threadIdx.x;
  const int w = t >> 6;
  const int l = t & 63;

  // Bijective chunked XCD swizzle (m204): consecutive work -> same XCD L2.
  const int nwg = gridDim.x;
  const int q = nwg >> 3, r8 = nwg & 7;
  const int xcd = blockIdx.x & 7, hi = blockIdx.x >> 3;
  const int wg = (xcd < r8 ? xcd * (q + 1) : r8 * (q + 1) + (xcd - r8) * q) + hi;
  const int v0 = wg * TILE;

  float* mySlab = accS + w * (TILE * 16);

  // zero own slab (wave-private)
  {
    float4 z = make_float4(0.f, 0.f, 0.f, 0.f);
    float4* a4 = (float4*)mySlab;
#pragma unroll
    for (int i = 0; i < 8; ++i) a4[l + i * 64] = z;
  }

  // ---- compaction pass 1: ballot masks per (tap, wave) ----
#pragma unroll
  for (int k = 0; k < KTAPS; ++k) {
    int id = (t < TILE) ? nbr[(size_t)k * NVOX + v0 + t] : -1;
    unsigned long long m = __ballot(id >= 0);
    if (l == 0 && w < 2) masksS[k * 2 + w] = m;
  }
  __syncthreads();
  // exclusive prefix over the 54 (tap,wave) counts -> pair offsets (wave 0)
  if (w == 0) {
    int c = (l < KTAPS * 2) ? __popcll(masksS[l]) : 0;
#pragma unroll
    for (int d = 1; d < 64; d <<= 1) { int o = __shfl_up(c, d); if (l >= d) c += o; }
    if (l < KTAPS * 2) woff[l + 1] = c;
    if (l == 0) woff[0] = 0;
  }
  __syncthreads();
  // ---- compaction pass 2: write (row, idx) pairs grouped by tap ----
#pragma unroll
  for (int k = 0; k < KTAPS; ++k) {
    int id = (t < TILE) ? nbr[(size_t)k * NVOX + v0 + t] : -1;
    if (id >= 0) {
      unsigned long long m = masksS[k * 2 + w];
      int pos = woff[k * 2 + w] + __popcll(m & ((1ull << l) - 1ull));
      if (pos < CAP) { pairRow[pos] = (unsigned short)t; pairIdx[pos] = id; }
    }
  }
  // chunk table: tap k -> ceil(cnt/16) chunks of <=16 rows (wave 0)
  if (w == 0) {
    int b0 = 0, cnt = 0;
    if (l < KTAPS) {
      b0 = min(woff[2 * l], CAP);
      cnt = min(woff[2 * l + 2], CAP) - b0;
    }
    int nch = (cnt + 15) >> 4;
    int inc = nch;
#pragma unroll
    for (int d = 1; d < 64; d <<= 1) { int o = __shfl_up(inc, d); if (l >= d) inc += o; }
    int base = inc - nch;
    for (int j = 0; j < nch; ++j) {
      int st = b0 + 16 * j;
      int ln = min(16, cnt - 16 * j);
      chunkTab[base + j] = ((unsigned)l << 16) | ((unsigned)st << 5) | (unsigned)ln;
    }
    if (l == KTAPS - 1) nChunksS = inc;
  }
  __syncthreads();
  const int nc = nChunksS;

  const int r16 = l & 15;   // chunk row (as MFMA N-col) / B cout-within-quadrant
  const int hk = l >> 4;    // 8-channel ci slice (fragment K position)
  const unsigned short* WtQ = Wt + (w * 16 + r16) * 64 + hk * 8;  // quadrant base

// Issue chunk cc: A gather (bf16, direct to fragment) + this wave's W frags.
#define ISSUE(Mv, A0v, A1v, W0v, W1v, cc) do {                         \
    if ((cc) < nc) {                                                   \
      Mv = chunkTab[(cc)];                                             \
      int st_ = (int)((Mv >> 5) & 0x7FFu);                             \
      int ln_ = (int)(Mv & 31u);                                       \
      int of_ = (r16 < ln_) ? r16 : 0;                                 \
      int ix_ = pairIdx[st_ + of_];                                    \
      const unsigned short* s_ = featsb + (size_t)ix_ * 64 + hk * 8;   \
      A0v = *(const uint4*)s_;                                         \
      A1v = *(const uint4*)(s_ + 32);                                  \
      const unsigned short* bp_ = WtQ + ((int)(Mv >> 16) << 12);       \
      W0v = *(const uint4*)bp_;                                        \
      W1v = *(const uint4*)(bp_ + 32);                                 \
    }                                                                  \
  } while (0)

// Consume: 2 MFMAs (W as A-operand!) + ONE float4 LDS read-modify-write.
// D layout: col(N)=l&15=chunk row, row(M)=hk*4+reg = cout-within-quadrant.
#define CONSUME(Mv, A0v, A1v, W0v, W1v) do {                                     \
    const int st_ = (int)((Mv >> 5) & 0x7FFu);                                   \
    const int ln_ = (int)(Mv & 31u);                                             \
    floatx4 z_ = {0.f, 0.f, 0.f, 0.f};                                           \
    floatx4 d_;                                                                  \
    d_ = __builtin_amdgcn_mfma_f32_16x16x32_bf16(                                \
        __builtin_bit_cast(bf16x8, W0v), __builtin_bit_cast(bf16x8, A0v), z_, 0, 0, 0); \
    d_ = __builtin_amdgcn_mfma_f32_16x16x32_bf16(                                \
        __builtin_bit_cast(bf16x8, W1v), __builtin_bit_cast(bf16x8, A1v), d_, 0, 0, 0); \
    if (r16 < ln_) {                                                             \
      int tr_ = pairRow[st_ + r16];                                              \
      float* p_ = mySlab + tr_ * 16 + hk * 4;                                    \
      float4 v_ = *(const float4*)p_;                                            \
      v_.x += d_[0]; v_.y += d_[1]; v_.z += d_[2]; v_.w += d_[3];                \
      *(float4*)p_ = v_;                                                         \
    }                                                                            \
  } while (0)

  if (FB) {
    // ---- 2-deep register pipeline over ALL chunks (this wave's quadrant) ----
    unsigned m0 = 0, m1 = 0;
    uint4 A00 = {0,0,0,0}, A01 = {0,0,0,0}, W00 = {0,0,0,0}, W01 = {0,0,0,0};
    uint4 A10 = {0,0,0,0}, A11 = {0,0,0,0}, W10 = {0,0,0,0}, W11 = {0,0,0,0};
    int c = 0;
    ISSUE(m0, A00, A01, W00, W01, 0);
    ISSUE(m1, A10, A11, W10, W11, 1);
    while (c < nc) {
      CONSUME(m0, A00, A01, W00, W01); ISSUE(m0, A00, A01, W00, W01, c + 2); ++c;
      if (c >= nc) break;
      CONSUME(m1, A10, A11, W10, W11); ISSUE(m1, A10, A11, W10, W11, c + 2); ++c;
    }
  } else {
    // Fallback (small workspace): serial fp32 gather + convert.
    for (int c = 0; c < nc; ++c) {
      unsigned m = chunkTab[c];
      int st = (int)((m >> 5) & 0x7FFu);
      int ln = (int)(m & 31u);
      int of = (r16 < ln) ? r16 : 0;
      int ix = pairIdx[st + of];
      const float* s = feats + (size_t)ix * 64 + hk * 8;
      float4 f0 = *(const float4*)s;
      float4 f1 = *(const float4*)(s + 4);
      float4 f2 = *(const float4*)(s + 32);
      float4 f3 = *(const float4*)(s + 36);
      uint4 A0, A1, W0, W1;
      A0.x = f2bf(f0.x) | (f2bf(f0.y) << 16);
      A0.y = f2bf(f0.z) | (f2bf(f0.w) << 16);
      A0.z = f2bf(f1.x) | (f2bf(f1.y) << 16);
      A0.w = f2bf(f1.z) | (f2bf(f1.w) << 16);
      A1.x = f2bf(f2.x) | (f2bf(f2.y) << 16);
      A1.y = f2bf(f2.z) | (f2bf(f2.w) << 16);
      A1.z = f2bf(f3.x) | (f2bf(f3.y) << 16);
      A1.w = f2bf(f3.z) | (f2bf(f3.w) << 16);
      const unsigned short* bp = WtQ + ((int)(m >> 16) << 12);
      W0 = *(const uint4*)bp;
      W1 = *(const uint4*)(bp + 32);
      CONSUME(m, A0, A1, W0, W1);
    }
  }
#undef ISSUE
#undef CONSUME

  // ---- epilogue: out = acc + bias (each (row,cout) lives in exactly one slab) ----
  __syncthreads();
  {
    int vox = t >> 1;
    int cb = (t & 1) * 32;
    float* op = out + (size_t)(v0 + vox) * 64 + cb;
#pragma unroll
    for (int qq = 0; qq < 8; ++qq) {
      int c0 = cb + qq * 4;
      const float* ap = accS + (c0 >> 4) * (TILE * 16) + vox * 16 + (c0 & 15);
      float4 v = *(const float4*)ap;
      float4 bv = *(const float4*)(bias + c0);
      v.x += bv.x; v.y += bv.y; v.z += bv.z; v.w += bv.w;
      *(float4*)(op + qq * 4) = v;
    }
  }
}

extern "C" void kernel_launch(void* const* d_in, const int* in_sizes, int n_in,
                              void* d_out, int out_size, void* d_ws, size_t ws_size,
                              hipStream_t stream) {
  const float* feats  = (const float*)d_in[0];
  const float* weight = (const float*)d_in[1];
  const float* bias   = (const float*)d_in[2];
  const int*   nbr    = (const int*)d_in[3];
  float* out = (float*)d_out;

  unsigned short* Wt = (unsigned short*)d_ws;   // 27*4096*2 = 221184 B
  const size_t featsOff = 256 * 1024;
  const size_t fbytes = (size_t)NVOX * 64 * 2;  // 51.2 MB
  const bool bigws = ws_size >= featsOff + fbytes;

  k_wt<<<432, 256, 0, stream>>>(weight, Wt);

  const int grid = NVOX / TILE;  // 3125
  if (bigws) {
    unsigned short* Fb = (unsigned short*)((char*)d_ws + featsOff);
    k_feats<<<6250, 256, 0, stream>>>((const float4*)feats, (uint2*)Fb);
    k_conv<true><<<grid, 256, 0, stream>>>(feats, Fb, Wt, bias, nbr, out);
  } else {
    k_conv<false><<<grid, 256, 0, stream>>>(feats, nullptr, Wt, bias, nbr, out);
  }
}

// Round 7
// 334.691 us; speedup vs baseline: 2.1067x; 1.3935x over previous
//
#include <hip/hip_runtime.h>
#include <stdint.h>

#define NVOX 400000
#define KTAPS 27
// CIN = COUT = 64

typedef __bf16 bf16x8 __attribute__((ext_vector_type(8)));
typedef float floatx16 __attribute__((ext_vector_type(16)));

__device__ __forceinline__ uint32_t f2bf(float f) {
  uint32_t u = __builtin_bit_cast(uint32_t, f);
  u += 0x7fffu + ((u >> 16) & 1u);
  return u >> 16;
}

__device__ __forceinline__ floatx16 zero16() {
  floatx16 z = {0.f,0.f,0.f,0.f,0.f,0.f,0.f,0.f,
                0.f,0.f,0.f,0.f,0.f,0.f,0.f,0.f};
  return z;
}

// Weight convert + transpose: Wt[k][co][ci] = bf16(W[k][ci][co]). 432 blocks.
__global__ void k_wt(const float* __restrict__ W, unsigned short* __restrict__ Wt) {
  int i = blockIdx.x * 256 + threadIdx.x;
  int k = i >> 12;
  int rem = i & 4095;
  int ci = rem >> 6;
  int co = rem & 63;
  Wt[(k << 12) + (co << 6) + ci] = (unsigned short)f2bf(W[i]);
}

// Feats convert: fp32 -> bf16, 4 float4 per thread. Grid 6250 blocks.
__global__ void k_feats(const float4* __restrict__ F, uint2* __restrict__ Fb) {
  int i0 = blockIdx.x * 1024 + threadIdx.x;
#pragma unroll
  for (int j = 0; j < 4; ++j) {
    int i = i0 + j * 256;
    float4 v = F[i];
    uint2 o;
    o.x = f2bf(v.x) | (f2bf(v.y) << 16);
    o.y = f2bf(v.z) | (f2bf(v.w) << 16);
    Fb[i] = o;
  }
}

// Main kernel: block = 256 threads = 4 waves; tile = 256 voxels x 64 couts.
// Software-pipelined: during tap k's MFMA phase we prefetch tap k+1's
// gathered A rows + B tile into registers and tap k+2's indices.
// R6/R7 changes vs the 181 us baseline:
//  (a) MASKED gathers: `if (id >= 0)` -> exec-masked load, invalid lanes
//      generate NO memory requests. 91% of gathered rows were invalid and
//      clamped to row 0 -> ~80% of vector-memory lane-requests eliminated.
//      (R0-R5 invariant: ~10-11 cy/CU per gathered 128B row across ALL
//      structures = TA lane-request throughput bound, ~1 lane-req/cy/CU.)
//      Zero-fill of invalid rows still happens at the LDS-write (unchanged).
//  (b) bijective XCD swizzle (m204; 1563 % 8 != 0) for gather L2 locality.
//  (c) rA zero-initialized at declaration (no formally-uninitialized reads).
template<bool FB>
__global__ __launch_bounds__(256, 3) void k_conv(
    const float* __restrict__ feats,
    const unsigned short* __restrict__ featsb,
    const unsigned short* __restrict__ Wt,     // [k][co][ci] bf16
    const float* __restrict__ bias,
    const int* __restrict__ nbr,               // [27][NVOX]
    float* __restrict__ out) {                 // [NVOX][64]

  __shared__ alignas(16) unsigned short lA[256 * 72]; // 36864 B
  __shared__ alignas(16) unsigned short lB[64 * 72];  //  9216 B

  const int t = threadIdx.x;
  const int w = t >> 6;
  const int l = t & 63;
  const int half = l >> 5;
  const int lm = l & 31;

  // Bijective chunked XCD swizzle (m204): consecutive tiles -> same XCD L2.
  const int nwg = gridDim.x;
  const int q = nwg >> 3, r8 = nwg & 7;
  const int xcd = blockIdx.x & 7, hi = blockIdx.x >> 3;
  const int wg = (xcd < r8 ? xcd * (q + 1) : r8 * (q + 1) + (xcd - r8) * q) + hi;
  const int v0 = wg * 256;

  floatx16 acc00 = zero16(), acc01 = zero16(), acc10 = zero16(), acc11 = zero16();

  const unsigned short* pA0 = &lA[(w * 64 + lm) * 72 + half * 8];
  const unsigned short* pA1 = pA0 + 32 * 72;
  const unsigned short* pB0 = &lB[lm * 72 + half * 8];
  const unsigned short* pB1 = pB0 + 32 * 72;

  const int rr = t >> 3;   // staging row within a 32-row pass
  const int cc = t & 7;    // 16 B chunk within a 128 B feat row

  // Per-thread staging geometry (constant across taps)
  int voff[8];
  bool vld[8];
#pragma unroll
  for (int p = 0; p < 8; ++p) {
    voff[p] = v0 + p * 32 + rr;
    vld[p] = voff[p] < NVOX;
  }
  const int brow = t >> 2;          // B staging row (cout)
  const int bcol = (t & 3) * 16;    // B staging col (ci)

  // ---- pipeline registers ----
  int idxA[8];   // indices for rows currently held in rA
  int idxN[8];   // indices for the next tap (gather addresses)
  uint4 rA[8] = {{0,0,0,0},{0,0,0,0},{0,0,0,0},{0,0,0,0},
                 {0,0,0,0},{0,0,0,0},{0,0,0,0},{0,0,0,0}};
  uint4 rB0, rB1;

  auto gather = [&](int id) -> uint4 {
    int sid = id < 0 ? 0 : id;
    if (FB) {
      return *(const uint4*)(featsb + (size_t)sid * 64 + cc * 8);
    } else {
      const float* s = feats + (size_t)sid * 64 + cc * 8;
      float4 f0 = *(const float4*)s;
      float4 f1 = *(const float4*)(s + 4);
      uint4 d;
      d.x = f2bf(f0.x) | (f2bf(f0.y) << 16);
      d.y = f2bf(f0.z) | (f2bf(f0.w) << 16);
      d.z = f2bf(f1.x) | (f2bf(f1.y) << 16);
      d.w = f2bf(f1.z) | (f2bf(f1.w) << 16);
      return d;
    }
  };

  // ---- prologue: indices tap0 -> gather tap0 + B tap0 -> indices tap1 ----
#pragma unroll
  for (int p = 0; p < 8; ++p) idxN[p] = vld[p] ? nbr[voff[p]] : -1;
  {
    const unsigned short* src = Wt + brow * 64 + bcol;
    rB0 = *(const uint4*)src;
    rB1 = *(const uint4*)(src + 8);
  }
#pragma unroll
  for (int p = 0; p < 8; ++p) {
    int id = idxN[p];
    idxA[p] = id;
    if (id >= 0) rA[p] = gather(id);   // masked: invalid lanes issue no request
  }
#pragma unroll
  for (int p = 0; p < 8; ++p) idxN[p] = vld[p] ? nbr[NVOX + voff[p]] : -1;

#pragma unroll 1
  for (int k = 0; k < KTAPS; ++k) {
    __syncthreads();   // previous tap's LDS reads done

    // ---- write phase: registers -> LDS (zero-mask invalid rows here) ----
#pragma unroll
    for (int p = 0; p < 8; ++p) {
      uint4 v = rA[p];
      if (idxA[p] < 0) { v.x = 0u; v.y = 0u; v.z = 0u; v.w = 0u; }
      *(uint4*)&lA[(p * 32 + rr) * 72 + cc * 8] = v;
    }
    {
      unsigned short* dst = &lB[brow * 72 + bcol];
      *(uint4*)dst = rB0;
      *(uint4*)(dst + 8) = rB1;
    }
    __syncthreads();   // LDS tiles ready

    // ---- prefetch phase for tap k+1 (overlaps the MFMA phase below) ----
    if (k + 1 < KTAPS) {
      const unsigned short* src = Wt + ((k + 1) << 12) + brow * 64 + bcol;
      rB0 = *(const uint4*)src;
      rB1 = *(const uint4*)(src + 8);
#pragma unroll
      for (int p = 0; p < 8; ++p) {
        int id = idxN[p];
        idxA[p] = id;
        if (id >= 0) rA[p] = gather(id);   // masked gather
      }
      if (k + 2 < KTAPS) {
        const int* nb = nbr + (size_t)(k + 2) * NVOX;
#pragma unroll
        for (int p = 0; p < 8; ++p) idxN[p] = vld[p] ? nb[voff[p]] : -1;
      }
    }

    // ---- MFMA phase: 4 K-chunks of 16 channels ----
#pragma unroll
    for (int kc = 0; kc < 4; ++kc) {
      bf16x8 a0 = *(const bf16x8*)(pA0 + kc * 16);
      bf16x8 a1 = *(const bf16x8*)(pA1 + kc * 16);
      bf16x8 b0 = *(const bf16x8*)(pB0 + kc * 16);
      bf16x8 b1 = *(const bf16x8*)(pB1 + kc * 16);
      acc00 = __builtin_amdgcn_mfma_f32_32x32x16_bf16(a0, b0, acc00, 0, 0, 0);
      acc01 = __builtin_amdgcn_mfma_f32_32x32x16_bf16(a0, b1, acc01, 0, 0, 0);
      acc10 = __builtin_amdgcn_mfma_f32_32x32x16_bf16(a1, b0, acc10, 0, 0, 0);
      acc11 = __builtin_amdgcn_mfma_f32_32x32x16_bf16(a1, b1, acc11, 0, 0, 0);
    }
  }

  // ---- epilogue: C/D layout col=lane&31 (cout), row=(reg&3)+8*(reg>>2)+4*half ----
  float bv0 = bias[lm];
  float bv1 = bias[32 + lm];
#pragma unroll
  for (int reg = 0; reg < 16; ++reg) {
    int m = (reg & 3) + 8 * (reg >> 2) + 4 * half;
    int vm0 = v0 + w * 64 + m;
    int vm1 = vm0 + 32;
    if (vm0 < NVOX) {
      out[vm0 * 64 + lm]      = acc00[reg] + bv0;
      out[vm0 * 64 + 32 + lm] = acc01[reg] + bv1;
    }
    if (vm1 < NVOX) {
      out[vm1 * 64 + lm]      = acc10[reg] + bv0;
      out[vm1 * 64 + 32 + lm] = acc11[reg] + bv1;
    }
  }
}

extern "C" void kernel_launch(void* const* d_in, const int* in_sizes, int n_in,
                              void* d_out, int out_size, void* d_ws, size_t ws_size,
                              hipStream_t stream) {
  const float* feats  = (const float*)d_in[0];
  const float* weight = (const float*)d_in[1];
  const float* bias   = (const float*)d_in[2];
  const int*   nbr    = (const int*)d_in[3];
  float* out = (float*)d_out;

  unsigned short* Wt = (unsigned short*)d_ws;
  const size_t featsOff = 256 * 1024;
  const size_t fbytes = (size_t)NVOX * 64 * 2;
  const bool bigws = ws_size >= featsOff + fbytes;

  k_wt<<<432, 256, 0, stream>>>(weight, Wt);

  const int grid = (NVOX + 255) / 256;  // 1563
  if (bigws) {
    unsigned short* Fb = (unsigned short*)((char*)d_ws + featsOff);
    k_feats<<<6250, 256, 0, stream>>>((const float4*)feats, (uint2*)Fb);
    k_conv<true><<<grid, 256, 0, stream>>>(feats, Fb, Wt, bias, nbr, out);
  } else {
    k_conv<false><<<grid, 256, 0, stream>>>(feats, nullptr, Wt, bias, nbr, out);
  }
}